// Round 9
// baseline (839.706 us; speedup 1.0000x reference)
//
#include <hip/hip_runtime.h>
#include <hip/hip_fp16.h>
#include <math.h>

#define N_NODES 100000
#define N_EDGES 3200000
#define INC 128
#define HID 64

constexpr int BLK = 256;
constexpr int NBLK_N = (N_NODES + BLK - 1) / BLK;   // 391
constexpr int NBLK_E = (N_EDGES + BLK - 1) / BLK;   // 12500

constexpr int NBUCK = (N_NODES + 127) / 128;        // 782 buckets of 128 dsts
constexpr int SUBC = 8;                             // sub-cursor sets (one per XCD)
constexpr int SUBCAP = 704;                         // mean 512 + 8.5 sigma
constexpr int NCUR = NBUCK * SUBC;                  // 6256

// cursor layout: k = xcd * NBUCK + b  -> each 128B line holds counters of ONE XCD
// (prevents cross-XCD atomic line migration, the round-7 limiter hypothesis).

// init cursors to sub-region bases; zero BN stats (3 layers x 128)
__global__ void init_k(int* __restrict__ cursor, float* __restrict__ stats) {
    int i = blockIdx.x * blockDim.x + threadIdx.x;
    if (i < NCUR) cursor[i] = i * SUBCAP;
    else if (i < NCUR + 384) stats[i - NCUR] = 0.f;
}

// append packed (src | dl<<17, ew) into bucket sub-regions; sub-cursor set = XCD.
__global__ void scatter_edges(const int* __restrict__ src, const int* __restrict__ dst,
                              const float* __restrict__ ew, int* __restrict__ cursor,
                              uint2* __restrict__ ebuf, int e) {
    int i = blockIdx.x * blockDim.x + threadIdx.x;
    if (i >= e) return;
    int xcd = blockIdx.x & (SUBC - 1);
    int d = __builtin_nontemporal_load(dst + i);
    int s = __builtin_nontemporal_load(src + i);
    float w = __builtin_nontemporal_load(ew + i);
    int b = d >> 7;
    int k = xcd * NBUCK + b;
    int slot = atomicAdd(&cursor[k], 1);
    uint2 v;
    v.x = (unsigned)s | ((unsigned)(d & 127) << 17);
    v.y = __float_as_uint(w);
    if (slot < (k + 1) * SUBCAP)  // statistically impossible overflow guard
        ebuf[slot] = v;
}

// exclusive scan of per-bucket totals (1 block, 1024 threads; NBUCK=782)
__global__ void bucket_scan(const int* __restrict__ cursor, int* __restrict__ bucketbase) {
    __shared__ int s[1024];
    int tid = threadIdx.x;
    int tot = 0;
    if (tid < NBUCK) {
        for (int c = 0; c < SUBC; ++c) {
            int k = c * NBUCK + tid;
            tot += min(cursor[k] - k * SUBCAP, SUBCAP);
        }
    }
    s[tid] = tot;
    __syncthreads();
    for (int d = 1; d < 1024; d <<= 1) {
        int t = (tid >= d) ? s[tid - d] : 0;
        __syncthreads();
        s[tid] += t;
        __syncthreads();
    }
    if (tid < NBUCK) bucketbase[tid] = s[tid] - tot;
}

// One block per bucket: count per-dst in LDS, scan, rewrite edges dst-sorted into a
// contiguous global window. CSR entry packed to 4B: src(17b) | fp16-ew-no-sign(15b).
__global__ __launch_bounds__(BLK) void build_csr(
    const uint2* __restrict__ ebuf, const int* __restrict__ cursor,
    const int* __restrict__ bucketbase, int* __restrict__ offs2,
    int* __restrict__ cntg, unsigned* __restrict__ csr)
{
    __shared__ int cntl[128];
    __shared__ int sc[128];
    __shared__ int pos[128];
    int b = blockIdx.x, tid = threadIdx.x;
    if (tid < 128) cntl[tid] = 0;
    __syncthreads();
    for (int c = 0; c < SUBC; ++c) {
        int k = c * NBUCK + b;
        int cn = min(cursor[k] - k * SUBCAP, SUBCAP);
        const unsigned long long* sub = (const unsigned long long*)(ebuf + (size_t)k * SUBCAP);
        for (int i = tid; i < cn; i += BLK) {
            unsigned long long ev = __builtin_nontemporal_load(sub + i);
            atomicAdd(&cntl[((unsigned)ev) >> 17], 1);
        }
    }
    __syncthreads();
    if (tid < 128) sc[tid] = cntl[tid];
    __syncthreads();
    for (int d = 1; d < 128; d <<= 1) {
        int t = (tid < 128 && tid >= d) ? sc[tid - d] : 0;
        __syncthreads();
        if (tid < 128) sc[tid] += t;
        __syncthreads();
    }
    int base = bucketbase[b];
    int node0 = b * 128;
    if (tid < 128) {
        int excl = sc[tid] - cntl[tid];
        pos[tid] = excl;
        if (node0 + tid < N_NODES) {
            offs2[node0 + tid] = base + excl;
            cntg[node0 + tid] = cntl[tid];
        }
    }
    __syncthreads();
    for (int c = 0; c < SUBC; ++c) {
        int k = c * NBUCK + b;
        int cn = min(cursor[k] - k * SUBCAP, SUBCAP);
        const unsigned long long* sub = (const unsigned long long*)(ebuf + (size_t)k * SUBCAP);
        for (int i = tid; i < cn; i += BLK) {
            unsigned long long ev = __builtin_nontemporal_load(sub + i);
            unsigned lo = (unsigned)ev;
            unsigned hi = (unsigned)(ev >> 32);
            int p = atomicAdd(&pos[lo >> 17], 1);
            unsigned short h15 = __half_as_ushort(__float2half_rn(__uint_as_float(hi)));
            csr[base + p] = (lo & 0x1FFFF) | ((unsigned)h15 << 17);
        }
    }
}

// Wave per dst node (grid-stride). lane = (edge-slot g=lane>>3, chan-block c8=lane&7).
// Per iteration: 8 edges x 16B row-chunks = 1KB in flight; no shfl in inner loop.
constexpr int AGG_GRID = 2048;
__global__ __launch_bounds__(BLK) void aggregate_bn(
    const __half* __restrict__ t, const int* __restrict__ offs2,
    const int* __restrict__ cntg, const unsigned* __restrict__ csr,
    const float* __restrict__ bias, float* __restrict__ h,
    float* __restrict__ stats, int n)
{
    int tid = threadIdx.x, lane = tid & 63, wid = tid >> 6;
    int g = lane >> 3, c8 = lane & 7;
    int gwave = blockIdx.x * 4 + wid;
    int nwaves = gridDim.x * 4;
    // per-lane bias for its 8 channels
    float4 bb0 = *(const float4*)(bias + c8 * 8);
    float4 bb1 = *(const float4*)(bias + c8 * 8 + 4);
    float bs[8], bs2[8];
#pragma unroll
    for (int j = 0; j < 8; ++j) { bs[j] = 0.f; bs2[j] = 0.f; }

    for (int node = gwave; node < n; node += nwaves) {
        int s0 = offs2[node], cn = cntg[node];
        float acc[8];
#pragma unroll
        for (int j = 0; j < 8; ++j) acc[j] = 0.f;
#pragma unroll 2
        for (int base = 0; base < cn; base += 8) {
            int ei = base + g;
            unsigned e = csr[s0 + min(ei, cn - 1)];
            float w = (ei < cn) ? __half2float(__ushort_as_half((unsigned short)(e >> 17))) : 0.f;
            int s = e & 0x1FFFF;
            uint4 pk = *(const uint4*)(t + (size_t)s * HID + c8 * 8);
            const __half2* hp = (const __half2*)&pk;
            float2 f0 = __half22float2(hp[0]);
            float2 f1 = __half22float2(hp[1]);
            float2 f2 = __half22float2(hp[2]);
            float2 f3 = __half22float2(hp[3]);
            acc[0] += w * f0.x; acc[1] += w * f0.y;
            acc[2] += w * f1.x; acc[3] += w * f1.y;
            acc[4] += w * f2.x; acc[5] += w * f2.y;
            acc[6] += w * f3.x; acc[7] += w * f3.y;
        }
        // reduce across the 8 edge-slots (xor over lane bits 3,4,5)
#pragma unroll
        for (int d = 8; d < 64; d <<= 1) {
#pragma unroll
            for (int j = 0; j < 8; ++j) acc[j] += __shfl_xor(acc[j], d, 64);
        }
        if (g == 0) {
            float v[8];
            v[0] = fmaxf(acc[0] + bb0.x, 0.f); v[1] = fmaxf(acc[1] + bb0.y, 0.f);
            v[2] = fmaxf(acc[2] + bb0.z, 0.f); v[3] = fmaxf(acc[3] + bb0.w, 0.f);
            v[4] = fmaxf(acc[4] + bb1.x, 0.f); v[5] = fmaxf(acc[5] + bb1.y, 0.f);
            v[6] = fmaxf(acc[6] + bb1.z, 0.f); v[7] = fmaxf(acc[7] + bb1.w, 0.f);
            float* hr = h + (size_t)node * HID + c8 * 8;
            *(float4*)hr = float4{v[0], v[1], v[2], v[3]};
            *(float4*)(hr + 4) = float4{v[4], v[5], v[6], v[7]};
#pragma unroll
            for (int j = 0; j < 8; ++j) { bs[j] += v[j]; bs2[j] += v[j] * v[j]; }
        }
    }
    __shared__ float r1[4][64], r2[4][64];
    if (g == 0) {
#pragma unroll
        for (int j = 0; j < 8; ++j) {
            r1[wid][c8 * 8 + j] = bs[j];
            r2[wid][c8 * 8 + j] = bs2[j];
        }
    }
    __syncthreads();
    if (tid < 64) {
        atomicAdd(&stats[tid], r1[0][tid] + r1[1][tid] + r1[2][tid] + r1[3][tid]);
        atomicAdd(&stats[64 + tid], r2[0][tid] + r2[1][tid] + r2[2][tid] + r2[3][tid]);
    }
}

__global__ void bn_finalize(const float* __restrict__ stats, const float* __restrict__ g,
                            const float* __restrict__ be, float* __restrict__ scsh, float n) {
    int c = threadIdx.x;
    if (c < 64) {
        float mean = stats[c] / n;
        float var = stats[64 + c] / n - mean * mean;
        float s = 1.0f / sqrtf(var + 1e-5f);
        float sc = g[c] * s;
        scsh[c] = sc;
        scsh[64 + c] = be[c] - mean * sc;
    }
}

// T[r,:] = half((trans? X*sc+sh : X)[r,:] @ W); one thread per row, W in LDS.
template <int IN, int OUT, bool TRANS>
__global__ __launch_bounds__(BLK) void mm_kernel(
    const float* __restrict__ X, const float* __restrict__ W,
    const float* __restrict__ scale, const float* __restrict__ shift,
    __half* __restrict__ T, int n)
{
    __shared__ float Wl[IN * OUT];
    for (int i = threadIdx.x; i < IN * OUT; i += BLK) Wl[i] = W[i];
    __shared__ float sc[IN], sh[IN];
    if (TRANS) {
        for (int i = threadIdx.x; i < IN; i += BLK) {
            sc[i] = scale[i];
            sh[i] = shift[i];
        }
    }
    __syncthreads();
    int r = blockIdx.x * BLK + threadIdx.x;
    if (r >= n) return;
    float acc[OUT];
#pragma unroll
    for (int j = 0; j < OUT; ++j) acc[j] = 0.f;
    const float4* x4 = reinterpret_cast<const float4*>(X + (size_t)r * IN);
#pragma unroll 2
    for (int k4 = 0; k4 < IN / 4; ++k4) {
        float4 xv = x4[k4];
        float xs[4] = {xv.x, xv.y, xv.z, xv.w};
#pragma unroll
        for (int u = 0; u < 4; ++u) {
            int k = k4 * 4 + u;
            float xk = xs[u];
            if (TRANS) xk = xk * sc[k] + sh[k];
#pragma unroll
            for (int j = 0; j < OUT; ++j) acc[j] += xk * Wl[k * OUT + j];
        }
    }
    unsigned short tmp[OUT];
#pragma unroll
    for (int j = 0; j < OUT; ++j) tmp[j] = __half_as_ushort(__float2half_rn(acc[j]));
    int4* dst4 = (int4*)(T + (size_t)r * OUT);
#pragma unroll
    for (int q = 0; q < OUT / 8; ++q) dst4[q] = ((int4*)tmp)[q];
}

__device__ __forceinline__ float gelu_f(float v) {
    return 0.5f * v * (1.0f + erff(v * 0.70710678118654752f));
}

// hb[r, half*64+jj] = half(gelu((x*sc+sh) @ W1 + b1)); column half per blockIdx.y
__global__ __launch_bounds__(BLK) void mlp1(
    const float* __restrict__ X, const float* __restrict__ W1,
    const float* __restrict__ B1, const float* __restrict__ scsh,
    __half* __restrict__ HB, int n)
{
    __shared__ float Wl[64 * 64];
    __shared__ float sc[64], sh[64], bl[64];
    int half_ = blockIdx.y;
    for (int i = threadIdx.x; i < 64 * 64; i += BLK) {
        int k = i >> 6, jj = i & 63;
        Wl[i] = W1[k * 128 + half_ * 64 + jj];
    }
    if (threadIdx.x < 64) {
        sc[threadIdx.x] = scsh[threadIdx.x];
        sh[threadIdx.x] = scsh[64 + threadIdx.x];
        bl[threadIdx.x] = B1[half_ * 64 + threadIdx.x];
    }
    __syncthreads();
    int r = blockIdx.x * BLK + threadIdx.x;
    if (r >= n) return;
    float acc[64];
#pragma unroll
    for (int j = 0; j < 64; ++j) acc[j] = 0.f;
    const float4* x4 = reinterpret_cast<const float4*>(X + (size_t)r * 64);
#pragma unroll 2
    for (int k4 = 0; k4 < 16; ++k4) {
        float4 xv = x4[k4];
        float xs[4] = {xv.x, xv.y, xv.z, xv.w};
#pragma unroll
        for (int u = 0; u < 4; ++u) {
            int k = k4 * 4 + u;
            float xk = xs[u] * sc[k] + sh[k];
#pragma unroll
            for (int j = 0; j < 64; ++j) acc[j] += xk * Wl[k * 64 + j];
        }
    }
    unsigned short tmp[64];
#pragma unroll
    for (int j = 0; j < 64; ++j)
        tmp[j] = __half_as_ushort(__float2half_rn(gelu_f(acc[j] + bl[j])));
    int4* dst4 = (int4*)(HB + (size_t)r * 128 + half_ * 64);
#pragma unroll
    for (int q = 0; q < 8; ++q) dst4[q] = ((int4*)tmp)[q];
}

// out[r,:] = gelu(hb @ W2 + b2) @ W3 + b3   (hb fp16)
__global__ __launch_bounds__(BLK) void mlp2(
    const __half* __restrict__ HB, const float* __restrict__ W2,
    const float* __restrict__ B2, const float* __restrict__ W3,
    const float* __restrict__ B3, float* __restrict__ Y, int n)
{
    __shared__ float Wl[128 * 64];
    __shared__ float W3l[64 * 5];
    __shared__ float b2l[64], b3l[8];
    for (int i = threadIdx.x; i < 128 * 64; i += BLK) Wl[i] = W2[i];
    for (int i = threadIdx.x; i < 64 * 5; i += BLK) W3l[i] = W3[i];
    if (threadIdx.x < 64) b2l[threadIdx.x] = B2[threadIdx.x];
    if (threadIdx.x < 5) b3l[threadIdx.x] = B3[threadIdx.x];
    __syncthreads();
    int r = blockIdx.x * BLK + threadIdx.x;
    if (r >= n) return;
    float acc[64];
#pragma unroll
    for (int j = 0; j < 64; ++j) acc[j] = 0.f;
    const int4* x4 = reinterpret_cast<const int4*>(HB + (size_t)r * 128);
#pragma unroll 2
    for (int q = 0; q < 16; ++q) {
        int4 pk = x4[q];
        unsigned w[4] = {(unsigned)pk.x, (unsigned)pk.y, (unsigned)pk.z, (unsigned)pk.w};
#pragma unroll
        for (int u = 0; u < 4; ++u) {
            float2 f2 = __half22float2(*(__half2*)&w[u]);
            float xs[2] = {f2.x, f2.y};
#pragma unroll
            for (int v = 0; v < 2; ++v) {
                int k = q * 8 + u * 2 + v;
                float xk = xs[v];
#pragma unroll
                for (int j = 0; j < 64; ++j) acc[j] += xk * Wl[k * 64 + j];
            }
        }
    }
    float o[5];
#pragma unroll
    for (int j = 0; j < 5; ++j) o[j] = b3l[j];
#pragma unroll
    for (int k = 0; k < 64; ++k) {
        float g = gelu_f(acc[k] + b2l[k]);
#pragma unroll
        for (int j = 0; j < 5; ++j) o[j] += g * W3l[k * 5 + j];
    }
    float* yr = Y + (size_t)r * 5;
#pragma unroll
    for (int j = 0; j < 5; ++j) yr[j] = o[j];
}

extern "C" void kernel_launch(void* const* d_in, const int* in_sizes, int n_in,
                              void* d_out, int out_size, void* d_ws, size_t ws_size,
                              hipStream_t stream)
{
    const float* x   = (const float*)d_in[0];
    const int*   ei  = (const int*)d_in[1];
    const int*   srcs = ei;
    const int*   dsts = ei + N_EDGES;
    const float* ew  = (const float*)d_in[2];
    const float* cw0 = (const float*)d_in[3];  const float* cb0 = (const float*)d_in[4];
    const float* cw1 = (const float*)d_in[5];  const float* cb1 = (const float*)d_in[6];
    const float* cw2 = (const float*)d_in[7];  const float* cb2 = (const float*)d_in[8];
    const float* g0  = (const float*)d_in[9];  const float* be0 = (const float*)d_in[10];
    const float* g1  = (const float*)d_in[11]; const float* be1 = (const float*)d_in[12];
    const float* g2  = (const float*)d_in[13]; const float* be2 = (const float*)d_in[14];
    const float* mw1 = (const float*)d_in[15]; const float* mb1 = (const float*)d_in[16];
    const float* mw2 = (const float*)d_in[17]; const float* mb2 = (const float*)d_in[18];
    const float* mw3 = (const float*)d_in[19]; const float* mb3 = (const float*)d_in[20];
    float* out = (float*)d_out;

    char* ws = (char*)d_ws;
    size_t off = 0;
    auto alloc = [&](size_t b) { size_t o = off; off = (off + b + 511) & ~(size_t)511; return o; };

    int*   cursor     = (int*)(ws + alloc((size_t)NCUR * 4));
    int*   bucketbase = (int*)(ws + alloc((size_t)(NBUCK + 1) * 4));
    float* stats      = (float*)(ws + alloc(3 * 128 * 4));
    float* scsh       = (float*)(ws + alloc(3 * 128 * 4));
    int*   offs2      = (int*)(ws + alloc((size_t)N_NODES * 4));
    int*   cntg       = (int*)(ws + alloc((size_t)N_NODES * 4));
    size_t o_csr      = alloc((size_t)N_EDGES * 4);                    // 12.8 MB
    unsigned* csr     = (unsigned*)(ws + o_csr);
    size_t o_t        = alloc((size_t)N_NODES * HID * 2);              // 12.8 MB
    __half* t         = (__half*)(ws + o_t);
    float* h          = (float*)(ws + alloc((size_t)N_NODES * HID * 4)); // 25.6 MB
    // ebuf (35.2 MB) aliases t+h (38.4 MB): dead before t/h are first written
    uint2* ebuf       = (uint2*)(ws + o_t);
    // hb fp16 (25.6 MB) aliases csr+t (25.6 MB): both dead after the last aggregate
    __half* hb        = (__half*)(ws + o_csr);

    // ---- staged edge sort -> packed dst-CSR (once per call) ----
    init_k<<<(NCUR + 384 + BLK - 1) / BLK, BLK, 0, stream>>>(cursor, stats);
    scatter_edges<<<NBLK_E, BLK, 0, stream>>>(srcs, dsts, ew, cursor, ebuf, N_EDGES);
    bucket_scan<<<1, 1024, 0, stream>>>(cursor, bucketbase);
    build_csr<<<NBUCK, BLK, 0, stream>>>(ebuf, cursor, bucketbase, offs2, cntg, csr);

    // ---- Layer 0 ----
    mm_kernel<INC, HID, false><<<NBLK_N, BLK, 0, stream>>>(x, cw0, nullptr, nullptr, t, N_NODES);
    aggregate_bn<<<AGG_GRID, BLK, 0, stream>>>(t, offs2, cntg, csr, cb0, h, stats, N_NODES);
    bn_finalize<<<1, 64, 0, stream>>>(stats, g0, be0, scsh, (float)N_NODES);

    // ---- Layer 1 ----
    mm_kernel<HID, HID, true><<<NBLK_N, BLK, 0, stream>>>(h, cw1, scsh, scsh + 64, t, N_NODES);
    aggregate_bn<<<AGG_GRID, BLK, 0, stream>>>(t, offs2, cntg, csr, cb1, h, stats + 128, N_NODES);
    bn_finalize<<<1, 64, 0, stream>>>(stats + 128, g1, be1, scsh + 128, (float)N_NODES);

    // ---- Layer 2 ----
    mm_kernel<HID, HID, true><<<NBLK_N, BLK, 0, stream>>>(h, cw2, scsh + 128, scsh + 192, t, N_NODES);
    aggregate_bn<<<AGG_GRID, BLK, 0, stream>>>(t, offs2, cntg, csr, cb2, h, stats + 256, N_NODES);
    bn_finalize<<<1, 64, 0, stream>>>(stats + 256, g2, be2, scsh + 256, (float)N_NODES);

    // ---- MLP ----
    mlp1<<<dim3(NBLK_N, 2), BLK, 0, stream>>>(h, mw1, mb1, scsh + 256, hb, N_NODES);
    mlp2<<<NBLK_N, BLK, 0, stream>>>(hb, mw2, mb2, mw3, mb3, out, N_NODES);
}

// Round 10
// 700.944 us; speedup vs baseline: 1.1980x; 1.1980x over previous
//
#include <hip/hip_runtime.h>
#include <hip/hip_fp16.h>
#include <math.h>

#define N_NODES 100000
#define N_EDGES 3200000
#define INC 128
#define HID 64

constexpr int BLK = 256;
constexpr int NBLK_N = (N_NODES + BLK - 1) / BLK;   // 391

constexpr int NBUCK = (N_NODES + 127) / 128;        // 782 buckets of 128 dsts
constexpr int CAP = 4608;                           // mean 4096 + 8 sigma
constexpr int CHUNK = 8192;
constexpr int NCHUNK = (N_EDGES + CHUNK - 1) / CHUNK; // 391

// init per-bucket cursors to absolute bucket bases; zero BN stats (3 layers x 128)
__global__ void init_k(int* __restrict__ cursor, float* __restrict__ stats) {
    int i = blockIdx.x * blockDim.x + threadIdx.x;
    if (i < NBUCK) cursor[i] = i * CAP;
    else if (i < NBUCK + 384) stats[i - NBUCK] = 0.f;
}

// One block per 8192-edge chunk: bucket-sort the chunk in LDS, reserve per-bucket
// space with ONE global atomic per non-empty bucket, flush coalesced (SoA 4B+2B).
__global__ __launch_bounds__(BLK) void sort_scatter(
    const int* __restrict__ src, const int* __restrict__ dst,
    const float* __restrict__ ew, int* __restrict__ gcur,
    unsigned* __restrict__ ebuf_lo, unsigned short* __restrict__ ebuf_ew)
{
    __shared__ unsigned s_lo[CHUNK];          // staging; front doubles as scan scratch
    __shared__ unsigned short s_ew[CHUNK];
    __shared__ int s_cnt[NBUCK];
    __shared__ int s_base[NBUCK];
    int tid = threadIdx.x;
    int c0 = blockIdx.x * CHUNK;
    int T = min(CHUNK, N_EDGES - c0);
    if (T <= 0) return;
    for (int i = tid; i < NBUCK; i += BLK) s_cnt[i] = 0;
    __syncthreads();
    // A: count per bucket
    for (int i = tid; i < T; i += BLK)
        atomicAdd(&s_cnt[dst[c0 + i] >> 7], 1);
    __syncthreads();
    // B: Hillis-Steele inclusive scan over 782 (ping-pong scratch inside s_lo)
    int* a = (int*)s_lo;
    int* b2 = a + 1024;
    for (int i = tid; i < NBUCK; i += BLK) a[i] = s_cnt[i];
    __syncthreads();
    for (int d = 1; d < NBUCK; d <<= 1) {
        for (int i = tid; i < NBUCK; i += BLK) b2[i] = a[i] + (i >= d ? a[i - d] : 0);
        __syncthreads();
        int* tmp = a; a = b2; b2 = tmp;
    }
    // reserve global space; s_base[b] maps sorted idx j -> bucket-relative slot
    for (int b = tid; b < NBUCK; b += BLK) {
        int cnt = s_cnt[b];
        int pex = a[b] - cnt;                 // exclusive prefix
        int gb = cnt ? (atomicAdd(&gcur[b], cnt) - b * CAP) : 0;
        s_base[b] = gb - pex;
        s_cnt[b] = pex;                       // becomes placement cursor
    }
    __syncthreads();
    // C: place edges into LDS in bucket-sorted order
    for (int i = tid; i < T; i += BLK) {
        int d = dst[c0 + i];
        int s = src[c0 + i];
        float w = ew[c0 + i];
        int b = d >> 7;
        int r = atomicAdd(&s_cnt[b], 1);
        s_lo[r] = (unsigned)s | ((unsigned)(d & 127) << 17);
        s_ew[r] = __half_as_ushort(__float2half_rn(w));
    }
    __syncthreads();
    // D: coalesced flush; s_cnt[b] is now the inclusive prefix end
    for (int j = tid; j < T; j += BLK) {
        int lo = 0, hi = NBUCK - 1;
        while (lo < hi) { int mid = (lo + hi) >> 1; if (s_cnt[mid] > j) hi = mid; else lo = mid + 1; }
        int b = lo;
        int rel = s_base[b] + j;              // slot within bucket region
        if (rel < CAP) {                      // statistically impossible overflow guard
            ebuf_lo[(size_t)b * CAP + rel] = s_lo[j];
            ebuf_ew[(size_t)b * CAP + rel] = s_ew[j];
        }
    }
}

// exclusive scan of per-bucket totals (1 block, 1024 threads; NBUCK=782)
__global__ void bucket_scan(const int* __restrict__ gcur, int* __restrict__ bucketbase) {
    __shared__ int s[1024];
    int tid = threadIdx.x;
    int tot = (tid < NBUCK) ? min(gcur[tid] - tid * CAP, CAP) : 0;
    s[tid] = tot;
    __syncthreads();
    for (int d = 1; d < 1024; d <<= 1) {
        int t = (tid >= d) ? s[tid - d] : 0;
        __syncthreads();
        s[tid] += t;
        __syncthreads();
    }
    if (tid < NBUCK) bucketbase[tid] = s[tid] - tot;
}

// One block per bucket: count per-dst in LDS, scan, rewrite edges dst-sorted into a
// contiguous global window. CSR entry packed to 4B: src(17b) | fp16-ew-no-sign(15b).
__global__ __launch_bounds__(BLK) void build_csr(
    const unsigned* __restrict__ ebuf_lo, const unsigned short* __restrict__ ebuf_ew,
    const int* __restrict__ gcur, const int* __restrict__ bucketbase,
    int* __restrict__ offs2, int* __restrict__ cntg, unsigned* __restrict__ csr)
{
    __shared__ int cntl[128];
    __shared__ int sc[128];
    __shared__ int pos[128];
    int b = blockIdx.x, tid = threadIdx.x;
    if (tid < 128) cntl[tid] = 0;
    __syncthreads();
    int cn = min(gcur[b] - b * CAP, CAP);
    const unsigned* lop = ebuf_lo + (size_t)b * CAP;
    const unsigned short* ewp = ebuf_ew + (size_t)b * CAP;
    for (int i = tid; i < cn; i += BLK) {
        unsigned lo = __builtin_nontemporal_load(lop + i);
        atomicAdd(&cntl[lo >> 17], 1);
    }
    __syncthreads();
    if (tid < 128) sc[tid] = cntl[tid];
    __syncthreads();
    for (int d = 1; d < 128; d <<= 1) {
        int t = (tid < 128 && tid >= d) ? sc[tid - d] : 0;
        __syncthreads();
        if (tid < 128) sc[tid] += t;
        __syncthreads();
    }
    int base = bucketbase[b];
    int node0 = b * 128;
    if (tid < 128) {
        int excl = sc[tid] - cntl[tid];
        pos[tid] = excl;
        if (node0 + tid < N_NODES) {
            offs2[node0 + tid] = base + excl;
            cntg[node0 + tid] = cntl[tid];
        }
    }
    __syncthreads();
    for (int i = tid; i < cn; i += BLK) {
        unsigned lo = __builtin_nontemporal_load(lop + i);
        unsigned short eh = ewp[i];
        int p = atomicAdd(&pos[lo >> 17], 1);
        csr[base + p] = (lo & 0x1FFFF) | ((unsigned)(eh & 0x7FFF) << 17);
    }
}

// Wave per dst node (grid-stride). lane = (edge-slot g=lane>>3, chan-block c8=lane&7).
// Per iteration: 8 edges x 16B row-chunks = 1KB in flight; no shfl in inner loop.
constexpr int AGG_GRID = 2048;
__global__ __launch_bounds__(BLK) void aggregate_bn(
    const __half* __restrict__ t, const int* __restrict__ offs2,
    const int* __restrict__ cntg, const unsigned* __restrict__ csr,
    const float* __restrict__ bias, float* __restrict__ h,
    float* __restrict__ stats, int n)
{
    int tid = threadIdx.x, lane = tid & 63, wid = tid >> 6;
    int g = lane >> 3, c8 = lane & 7;
    int gwave = blockIdx.x * 4 + wid;
    int nwaves = gridDim.x * 4;
    float4 bb0 = *(const float4*)(bias + c8 * 8);
    float4 bb1 = *(const float4*)(bias + c8 * 8 + 4);
    float bs[8], bs2[8];
#pragma unroll
    for (int j = 0; j < 8; ++j) { bs[j] = 0.f; bs2[j] = 0.f; }

    for (int node = gwave; node < n; node += nwaves) {
        int s0 = offs2[node], cn = cntg[node];
        float acc[8];
#pragma unroll
        for (int j = 0; j < 8; ++j) acc[j] = 0.f;
#pragma unroll 2
        for (int base = 0; base < cn; base += 8) {
            int ei = base + g;
            unsigned e = csr[s0 + min(ei, cn - 1)];
            float w = (ei < cn) ? __half2float(__ushort_as_half((unsigned short)(e >> 17))) : 0.f;
            int s = e & 0x1FFFF;
            uint4 pk = *(const uint4*)(t + (size_t)s * HID + c8 * 8);
            const __half2* hp = (const __half2*)&pk;
            float2 f0 = __half22float2(hp[0]);
            float2 f1 = __half22float2(hp[1]);
            float2 f2 = __half22float2(hp[2]);
            float2 f3 = __half22float2(hp[3]);
            acc[0] += w * f0.x; acc[1] += w * f0.y;
            acc[2] += w * f1.x; acc[3] += w * f1.y;
            acc[4] += w * f2.x; acc[5] += w * f2.y;
            acc[6] += w * f3.x; acc[7] += w * f3.y;
        }
#pragma unroll
        for (int d = 8; d < 64; d <<= 1) {
#pragma unroll
            for (int j = 0; j < 8; ++j) acc[j] += __shfl_xor(acc[j], d, 64);
        }
        if (g == 0) {
            float v[8];
            v[0] = fmaxf(acc[0] + bb0.x, 0.f); v[1] = fmaxf(acc[1] + bb0.y, 0.f);
            v[2] = fmaxf(acc[2] + bb0.z, 0.f); v[3] = fmaxf(acc[3] + bb0.w, 0.f);
            v[4] = fmaxf(acc[4] + bb1.x, 0.f); v[5] = fmaxf(acc[5] + bb1.y, 0.f);
            v[6] = fmaxf(acc[6] + bb1.z, 0.f); v[7] = fmaxf(acc[7] + bb1.w, 0.f);
            float* hr = h + (size_t)node * HID + c8 * 8;
            *(float4*)hr = float4{v[0], v[1], v[2], v[3]};
            *(float4*)(hr + 4) = float4{v[4], v[5], v[6], v[7]};
#pragma unroll
            for (int j = 0; j < 8; ++j) { bs[j] += v[j]; bs2[j] += v[j] * v[j]; }
        }
    }
    __shared__ float r1[4][64], r2[4][64];
    if (g == 0) {
#pragma unroll
        for (int j = 0; j < 8; ++j) {
            r1[wid][c8 * 8 + j] = bs[j];
            r2[wid][c8 * 8 + j] = bs2[j];
        }
    }
    __syncthreads();
    if (tid < 64) {
        atomicAdd(&stats[tid], r1[0][tid] + r1[1][tid] + r1[2][tid] + r1[3][tid]);
        atomicAdd(&stats[64 + tid], r2[0][tid] + r2[1][tid] + r2[2][tid] + r2[3][tid]);
    }
}

__global__ void bn_finalize(const float* __restrict__ stats, const float* __restrict__ g,
                            const float* __restrict__ be, float* __restrict__ scsh, float n) {
    int c = threadIdx.x;
    if (c < 64) {
        float mean = stats[c] / n;
        float var = stats[64 + c] / n - mean * mean;
        float s = 1.0f / sqrtf(var + 1e-5f);
        float sc = g[c] * s;
        scsh[c] = sc;
        scsh[64 + c] = be[c] - mean * sc;
    }
}

// T[r,:] = half((trans? X*sc+sh : X)[r,:] @ W); one thread per row, W in LDS.
template <int IN, int OUT, bool TRANS>
__global__ __launch_bounds__(BLK) void mm_kernel(
    const float* __restrict__ X, const float* __restrict__ W,
    const float* __restrict__ scale, const float* __restrict__ shift,
    __half* __restrict__ T, int n)
{
    __shared__ float Wl[IN * OUT];
    for (int i = threadIdx.x; i < IN * OUT; i += BLK) Wl[i] = W[i];
    __shared__ float sc[IN], sh[IN];
    if (TRANS) {
        for (int i = threadIdx.x; i < IN; i += BLK) {
            sc[i] = scale[i];
            sh[i] = shift[i];
        }
    }
    __syncthreads();
    int r = blockIdx.x * BLK + threadIdx.x;
    if (r >= n) return;
    float acc[OUT];
#pragma unroll
    for (int j = 0; j < OUT; ++j) acc[j] = 0.f;
    const float4* x4 = reinterpret_cast<const float4*>(X + (size_t)r * IN);
#pragma unroll 2
    for (int k4 = 0; k4 < IN / 4; ++k4) {
        float4 xv = x4[k4];
        float xs[4] = {xv.x, xv.y, xv.z, xv.w};
#pragma unroll
        for (int u = 0; u < 4; ++u) {
            int k = k4 * 4 + u;
            float xk = xs[u];
            if (TRANS) xk = xk * sc[k] + sh[k];
#pragma unroll
            for (int j = 0; j < OUT; ++j) acc[j] += xk * Wl[k * OUT + j];
        }
    }
    unsigned short tmp[OUT];
#pragma unroll
    for (int j = 0; j < OUT; ++j) tmp[j] = __half_as_ushort(__float2half_rn(acc[j]));
    int4* dst4 = (int4*)(T + (size_t)r * OUT);
#pragma unroll
    for (int q = 0; q < OUT / 8; ++q) dst4[q] = ((int4*)tmp)[q];
}

__device__ __forceinline__ float gelu_f(float v) {
    return 0.5f * v * (1.0f + erff(v * 0.70710678118654752f));
}

// hb[r, half*64+jj] = half(gelu((x*sc+sh) @ W1 + b1)); column half per blockIdx.y
__global__ __launch_bounds__(BLK) void mlp1(
    const float* __restrict__ X, const float* __restrict__ W1,
    const float* __restrict__ B1, const float* __restrict__ scsh,
    __half* __restrict__ HB, int n)
{
    __shared__ float Wl[64 * 64];
    __shared__ float sc[64], sh[64], bl[64];
    int half_ = blockIdx.y;
    for (int i = threadIdx.x; i < 64 * 64; i += BLK) {
        int k = i >> 6, jj = i & 63;
        Wl[i] = W1[k * 128 + half_ * 64 + jj];
    }
    if (threadIdx.x < 64) {
        sc[threadIdx.x] = scsh[threadIdx.x];
        sh[threadIdx.x] = scsh[64 + threadIdx.x];
        bl[threadIdx.x] = B1[half_ * 64 + threadIdx.x];
    }
    __syncthreads();
    int r = blockIdx.x * BLK + threadIdx.x;
    if (r >= n) return;
    float acc[64];
#pragma unroll
    for (int j = 0; j < 64; ++j) acc[j] = 0.f;
    const float4* x4 = reinterpret_cast<const float4*>(X + (size_t)r * 64);
#pragma unroll 2
    for (int k4 = 0; k4 < 16; ++k4) {
        float4 xv = x4[k4];
        float xs[4] = {xv.x, xv.y, xv.z, xv.w};
#pragma unroll
        for (int u = 0; u < 4; ++u) {
            int k = k4 * 4 + u;
            float xk = xs[u] * sc[k] + sh[k];
#pragma unroll
            for (int j = 0; j < 64; ++j) acc[j] += xk * Wl[k * 64 + j];
        }
    }
    unsigned short tmp[64];
#pragma unroll
    for (int j = 0; j < 64; ++j)
        tmp[j] = __half_as_ushort(__float2half_rn(gelu_f(acc[j] + bl[j])));
    int4* dst4 = (int4*)(HB + (size_t)r * 128 + half_ * 64);
#pragma unroll
    for (int q = 0; q < 8; ++q) dst4[q] = ((int4*)tmp)[q];
}

// out[r,:] = gelu(hb @ W2 + b2) @ W3 + b3   (hb fp16)
__global__ __launch_bounds__(BLK) void mlp2(
    const __half* __restrict__ HB, const float* __restrict__ W2,
    const float* __restrict__ B2, const float* __restrict__ W3,
    const float* __restrict__ B3, float* __restrict__ Y, int n)
{
    __shared__ float Wl[128 * 64];
    __shared__ float W3l[64 * 5];
    __shared__ float b2l[64], b3l[8];
    for (int i = threadIdx.x; i < 128 * 64; i += BLK) Wl[i] = W2[i];
    for (int i = threadIdx.x; i < 64 * 5; i += BLK) W3l[i] = W3[i];
    if (threadIdx.x < 64) b2l[threadIdx.x] = B2[threadIdx.x];
    if (threadIdx.x < 5) b3l[threadIdx.x] = B3[threadIdx.x];
    __syncthreads();
    int r = blockIdx.x * BLK + threadIdx.x;
    if (r >= n) return;
    float acc[64];
#pragma unroll
    for (int j = 0; j < 64; ++j) acc[j] = 0.f;
    const int4* x4 = reinterpret_cast<const int4*>(HB + (size_t)r * 128);
#pragma unroll 2
    for (int q = 0; q < 16; ++q) {
        int4 pk = x4[q];
        unsigned w[4] = {(unsigned)pk.x, (unsigned)pk.y, (unsigned)pk.z, (unsigned)pk.w};
#pragma unroll
        for (int u = 0; u < 4; ++u) {
            float2 f2 = __half22float2(*(__half2*)&w[u]);
            float xs[2] = {f2.x, f2.y};
#pragma unroll
            for (int v = 0; v < 2; ++v) {
                int k = q * 8 + u * 2 + v;
                float xk = xs[v];
#pragma unroll
                for (int j = 0; j < 64; ++j) acc[j] += xk * Wl[k * 64 + j];
            }
        }
    }
    float o[5];
#pragma unroll
    for (int j = 0; j < 5; ++j) o[j] = b3l[j];
#pragma unroll
    for (int k = 0; k < 64; ++k) {
        float g = gelu_f(acc[k] + b2l[k]);
#pragma unroll
        for (int j = 0; j < 5; ++j) o[j] += g * W3l[k * 5 + j];
    }
    float* yr = Y + (size_t)r * 5;
#pragma unroll
    for (int j = 0; j < 5; ++j) yr[j] = o[j];
}

extern "C" void kernel_launch(void* const* d_in, const int* in_sizes, int n_in,
                              void* d_out, int out_size, void* d_ws, size_t ws_size,
                              hipStream_t stream)
{
    const float* x   = (const float*)d_in[0];
    const int*   ei  = (const int*)d_in[1];
    const int*   srcs = ei;
    const int*   dsts = ei + N_EDGES;
    const float* ew  = (const float*)d_in[2];
    const float* cw0 = (const float*)d_in[3];  const float* cb0 = (const float*)d_in[4];
    const float* cw1 = (const float*)d_in[5];  const float* cb1 = (const float*)d_in[6];
    const float* cw2 = (const float*)d_in[7];  const float* cb2 = (const float*)d_in[8];
    const float* g0  = (const float*)d_in[9];  const float* be0 = (const float*)d_in[10];
    const float* g1  = (const float*)d_in[11]; const float* be1 = (const float*)d_in[12];
    const float* g2  = (const float*)d_in[13]; const float* be2 = (const float*)d_in[14];
    const float* mw1 = (const float*)d_in[15]; const float* mb1 = (const float*)d_in[16];
    const float* mw2 = (const float*)d_in[17]; const float* mb2 = (const float*)d_in[18];
    const float* mw3 = (const float*)d_in[19]; const float* mb3 = (const float*)d_in[20];
    float* out = (float*)d_out;

    char* ws = (char*)d_ws;
    size_t off = 0;
    auto alloc = [&](size_t b) { size_t o = off; off = (off + b + 511) & ~(size_t)511; return o; };

    int*   cursor     = (int*)(ws + alloc((size_t)NBUCK * 4));
    int*   bucketbase = (int*)(ws + alloc((size_t)(NBUCK + 1) * 4));
    float* stats      = (float*)(ws + alloc(3 * 128 * 4));
    float* scsh       = (float*)(ws + alloc(3 * 128 * 4));
    int*   offs2      = (int*)(ws + alloc((size_t)N_NODES * 4));
    int*   cntg       = (int*)(ws + alloc((size_t)N_NODES * 4));
    size_t o_csr      = alloc((size_t)N_EDGES * 4);                    // 12.8 MB
    unsigned* csr     = (unsigned*)(ws + o_csr);
    size_t o_t        = alloc((size_t)N_NODES * HID * 2);              // 12.8 MB
    __half* t         = (__half*)(ws + o_t);
    float* h          = (float*)(ws + alloc((size_t)N_NODES * HID * 4)); // 25.6 MB
    // ebuf SoA (14.4 + 7.2 MB) aliases t+h (38.4 MB): dead before t/h first written
    unsigned*       ebuf_lo = (unsigned*)(ws + o_t);
    unsigned short* ebuf_ew = (unsigned short*)(ws + o_t + (size_t)NBUCK * CAP * 4);
    // hb fp16 (25.6 MB) aliases csr+t (25.6 MB): both dead after the last aggregate
    __half* hb        = (__half*)(ws + o_csr);

    // ---- chunk-sorted edge scatter -> packed dst-CSR (once per call) ----
    init_k<<<(NBUCK + 384 + BLK - 1) / BLK, BLK, 0, stream>>>(cursor, stats);
    sort_scatter<<<NCHUNK, BLK, 0, stream>>>(srcs, dsts, ew, cursor, ebuf_lo, ebuf_ew);
    bucket_scan<<<1, 1024, 0, stream>>>(cursor, bucketbase);
    build_csr<<<NBUCK, BLK, 0, stream>>>(ebuf_lo, ebuf_ew, cursor, bucketbase, offs2, cntg, csr);

    // ---- Layer 0 ----
    mm_kernel<INC, HID, false><<<NBLK_N, BLK, 0, stream>>>(x, cw0, nullptr, nullptr, t, N_NODES);
    aggregate_bn<<<AGG_GRID, BLK, 0, stream>>>(t, offs2, cntg, csr, cb0, h, stats, N_NODES);
    bn_finalize<<<1, 64, 0, stream>>>(stats, g0, be0, scsh, (float)N_NODES);

    // ---- Layer 1 ----
    mm_kernel<HID, HID, true><<<NBLK_N, BLK, 0, stream>>>(h, cw1, scsh, scsh + 64, t, N_NODES);
    aggregate_bn<<<AGG_GRID, BLK, 0, stream>>>(t, offs2, cntg, csr, cb1, h, stats + 128, N_NODES);
    bn_finalize<<<1, 64, 0, stream>>>(stats + 128, g1, be1, scsh + 128, (float)N_NODES);

    // ---- Layer 2 ----
    mm_kernel<HID, HID, true><<<NBLK_N, BLK, 0, stream>>>(h, cw2, scsh + 128, scsh + 192, t, N_NODES);
    aggregate_bn<<<AGG_GRID, BLK, 0, stream>>>(t, offs2, cntg, csr, cb2, h, stats + 256, N_NODES);
    bn_finalize<<<1, 64, 0, stream>>>(stats + 256, g2, be2, scsh + 256, (float)N_NODES);

    // ---- MLP ----
    mlp1<<<dim3(NBLK_N, 2), BLK, 0, stream>>>(h, mw1, mb1, scsh + 256, hb, N_NODES);
    mlp2<<<NBLK_N, BLK, 0, stream>>>(hb, mw2, mb2, mw3, mb3, out, N_NODES);
}